// Round 4
// baseline (651.694 us; speedup 1.0000x reference)
//
#include <hip/hip_runtime.h>
#include <hip/hip_bf16.h>
#include <math.h>

// Problem constants (fixed by the reference)
#define NN       10000      // nodes
#define F_IN     128
#define HID      300
#define H1       5
#define H3       3
#define NCLS     40
#define HC1      (H1*HID)   // 1500
#define HC3      (H3*NCLS)  // 120
#define KPAD     1504       // 1500 padded to multiple of 32 (16B-aligned bf16 rows)
#define LD3      128        // layer-3 feature stride (120 padded)
#define NEG_SLOPE 0.2f
#define EPSV     1e-16f

typedef __attribute__((ext_vector_type(8))) short bf16x8;
typedef __attribute__((ext_vector_type(8))) unsigned short u16x8;
typedef __attribute__((ext_vector_type(4))) float f32x4;

__device__ inline unsigned short f2bf(float f) {
  unsigned int u = __builtin_bit_cast(unsigned int, f);
  unsigned int r = (u + 0x7FFFu + ((u >> 16) & 1u)) >> 16;   // RNE
  return (unsigned short)r;
}
__device__ inline float bf2f(unsigned short s) {
  unsigned int u = ((unsigned int)s) << 16;
  return __builtin_bit_cast(float, u);
}

// async 16B/lane global->LDS (lds dest = wave-uniform base + lane*16)
__device__ __forceinline__ void gl2lds16(const unsigned short* g, unsigned short* l) {
  __builtin_amdgcn_global_load_lds(
      (const __attribute__((address_space(1))) unsigned int*)(const void*)g,
      (__attribute__((address_space(3))) unsigned int*)(void*)l, 16, 0, 0);
}

// ---------------------------------------------------------------------------
// CSR build
// ---------------------------------------------------------------------------
__global__ void k_count(const int* __restrict__ ei, int* __restrict__ counts,
                        int E0, int Etot) {
  int e = blockIdx.x * 256 + threadIdx.x;
  if (e >= Etot) return;
  int dst = (e < E0) ? ei[E0 + e] : (e - E0);
  atomicAdd(&counts[dst], 1);
}

__global__ __launch_bounds__(256) void k_scan(const int* __restrict__ counts,
                                              int* __restrict__ offsets,
                                              int* __restrict__ cursor,
                                              int N, int Etot) {
  __shared__ int sh[256];
  const int CH = 40;  // 256*40 = 10240 >= N
  int t = threadIdx.x;
  int base = t * CH;
  int s = 0;
  for (int i = 0; i < CH; i++) {
    int idx = base + i;
    if (idx < N) s += counts[idx];
  }
  sh[t] = s;
  __syncthreads();
  for (int d = 1; d < 256; d <<= 1) {
    int v = (t >= d) ? sh[t - d] : 0;
    __syncthreads();
    sh[t] += v;
    __syncthreads();
  }
  int run = sh[t] - s;  // exclusive prefix
  for (int i = 0; i < CH; i++) {
    int idx = base + i;
    if (idx < N) {
      offsets[idx] = run;
      cursor[idx] = run;
      run += counts[idx];
    }
  }
  if (t == 0) offsets[N] = Etot;
}

__global__ void k_scatter(const int* __restrict__ ei, int* __restrict__ cursor,
                          int* __restrict__ csr_src, int E0, int Etot) {
  int e = blockIdx.x * 256 + threadIdx.x;
  if (e >= Etot) return;
  int src, dst;
  if (e < E0) { src = ei[e]; dst = ei[E0 + e]; }
  else        { src = dst = e - E0; }
  int pos = atomicAdd(&cursor[dst], 1);
  csr_src[pos] = src;
}

// ---------------------------------------------------------------------------
// fp32 -> bf16 casts
// ---------------------------------------------------------------------------
__global__ void k_cvt(const float* __restrict__ in, unsigned short* __restrict__ out,
                      int R, int C, int Cpad) {
  long long idx = (long long)blockIdx.x * 256 + threadIdx.x;
  if (idx >= (long long)R * Cpad) return;
  int r = (int)(idx / Cpad), c = (int)(idx - (long long)r * Cpad);
  out[idx] = (c < C) ? f2bf(in[(size_t)r * C + c]) : 0;
}

// in: [K][Nmat] row-major -> out: [Nmat][Kpad] (transposed, zero-padded)
// 64x64 LDS tile, coalesced on both sides.
__global__ __launch_bounds__(256) void k_cvtT(const float* __restrict__ in,
                                              unsigned short* __restrict__ out,
                                              int K, int Nmat, int Kpad) {
  __shared__ float tile[64][65];
  int kt = blockIdx.y * 64, nt = blockIdx.x * 64;
  int c = threadIdx.x & 63, r = threadIdx.x >> 6;  // 4 rows per pass
  for (int rr = r; rr < 64; rr += 4) {
    int k = kt + rr, n = nt + c;
    tile[rr][c] = (k < K && n < Nmat) ? in[(size_t)k * Nmat + n] : 0.f;
  }
  __syncthreads();
  for (int rr = r; rr < 64; rr += 4) {
    int n = nt + rr, k = kt + c;
    if (n < Nmat && k < Kpad) out[(size_t)n * Kpad + k] = f2bf(tile[c][rr]);
  }
}

// ---------------------------------------------------------------------------
// MFMA GEMM (m97 structure): Cbf[M,ldc] = A[M,Kpad] @ Bt[Nmat,Kpad]^T, bf16 out.
// 128x128 tile, BK=32, 256 thr = 4 waves (2x2), each wave 4x4 of 16x16x32.
// LDS is fragment-ordered: chunk c (1KB) = rows [c*16,c*16+16); lane l's 16B
// = row c*16+(l&15), k-seg (l>>4)*8.  global_load_lds width=16 staging;
// ds_read_b128 at chunk+lane*16 is conflict-free.
// ---------------------------------------------------------------------------
#define BM 128
#define BN 128
#define BK 32

__global__ __launch_bounds__(256) void gemm_mfma(
    const unsigned short* __restrict__ A,   // [M][Kpad]
    const unsigned short* __restrict__ Bt,  // [Nmat][Kpad]
    unsigned short* __restrict__ Cbf,       // [M][ldc]
    int M, int Kpad, int Nmat, int ldc) {
  __shared__ unsigned short As[BM * BK];  // 8 KB
  __shared__ unsigned short Bs[BN * BK];  // 8 KB
  int tid = threadIdx.x;
  int lane = tid & 63, wid = tid >> 6;
  int wm = wid >> 1, wn = wid & 1;
  int bm = blockIdx.y * BM, bn = blockIdx.x * BN;
  int quad = lane >> 4, l16 = lane & 15;
  int kq = quad * 8;

  // staging: wave w stages chunks w and w+4 of both A and B tiles
  int ar0 = min(bm + wid * 16 + l16, M - 1);
  int ar1 = min(bm + (wid + 4) * 16 + l16, M - 1);
  int br0 = min(bn + wid * 16 + l16, Nmat - 1);
  int br1 = min(bn + (wid + 4) * 16 + l16, Nmat - 1);
  const unsigned short* ga0 = A + (size_t)ar0 * Kpad + kq;
  const unsigned short* ga1 = A + (size_t)ar1 * Kpad + kq;
  const unsigned short* gb0 = Bt + (size_t)br0 * Kpad + kq;
  const unsigned short* gb1 = Bt + (size_t)br1 * Kpad + kq;
  unsigned short* la0 = As + wid * 512;        // wave-uniform chunk bases
  unsigned short* la1 = As + (wid + 4) * 512;
  unsigned short* lb0 = Bs + wid * 512;
  unsigned short* lb1 = Bs + (wid + 4) * 512;

  f32x4 acc[4][4] = {};

  for (int kt = 0; kt < Kpad; kt += BK) {
    gl2lds16(ga0 + kt, la0);
    gl2lds16(ga1 + kt, la1);
    gl2lds16(gb0 + kt, lb0);
    gl2lds16(gb1 + kt, lb1);
    __syncthreads();
    bf16x8 af[4], bfr[4];
#pragma unroll
    for (int i = 0; i < 4; i++) {
      af[i]  = *(const bf16x8*)(As + (wm * 4 + i) * 512 + lane * 8);
      bfr[i] = *(const bf16x8*)(Bs + (wn * 4 + i) * 512 + lane * 8);
    }
#pragma unroll
    for (int i = 0; i < 4; i++)
#pragma unroll
      for (int j = 0; j < 4; j++)
        acc[i][j] = __builtin_amdgcn_mfma_f32_16x16x32_bf16(af[i], bfr[j], acc[i][j], 0, 0, 0);
    __syncthreads();
  }

#pragma unroll
  for (int i = 0; i < 4; i++) {
    int rowb = bm + wm * 64 + i * 16 + quad * 4;
#pragma unroll
    for (int j = 0; j < 4; j++) {
      int col = bn + wn * 64 + j * 16 + l16;
      if (col < ldc) {
        bool live = col < Nmat;
#pragma unroll
        for (int r = 0; r < 4; r++) {
          int row = rowb + r;
          if (row < M) Cbf[(size_t)row * ldc + col] = live ? f2bf(acc[i][j][r]) : 0;
        }
      }
    }
  }
}

// ---------------------------------------------------------------------------
// Attention coefficients from bf16 features
// ---------------------------------------------------------------------------
__global__ __launch_bounds__(64) void k_att(const unsigned short* __restrict__ hfeat,
                                            int ldh,
                                            const float* __restrict__ att_s,
                                            const float* __restrict__ att_d,
                                            float* __restrict__ asrc,
                                            float* __restrict__ adst,
                                            int H, int C) {
  int n = blockIdx.x;
  int t = threadIdx.x;
  const unsigned short* hr = hfeat + (size_t)n * ldh;
  for (int h = 0; h < H; h++) {
    float ps = 0.f, pd = 0.f;
    for (int c = t; c < C; c += 64) {
      float v = bf2f(hr[h * C + c]);
      ps += v * att_s[h * C + c];
      pd += v * att_d[h * C + c];
    }
    for (int o = 32; o > 0; o >>= 1) {
      ps += __shfl_down(ps, o);
      pd += __shfl_down(pd, o);
    }
    if (t == 0) {
      asrc[n * H + h] = ps;
      adst[n * H + h] = pd;
    }
  }
}

// ---------------------------------------------------------------------------
// Per-(node,head) softmax over incoming edges; writes normalized alpha.
// ---------------------------------------------------------------------------
__global__ void k_stats(const float* __restrict__ asrc,
                        const float* __restrict__ adst,
                        const int* __restrict__ csr_src,
                        const int* __restrict__ offsets,
                        float* __restrict__ alpha, int N, int H) {
  int t = blockIdx.x * 256 + threadIdx.x;
  if (t >= N * H) return;
  int n = t / H, h = t - n * H;
  int s0 = offsets[n], s1 = offsets[n + 1];
  float ad = adst[t];
  float m = -1e30f;
  for (int p = s0; p < s1; p++) {
    float v = asrc[csr_src[p] * H + h] + ad;
    v = v > 0.f ? v : NEG_SLOPE * v;
    m = fmaxf(m, v);
  }
  float sum = 0.f;
  for (int p = s0; p < s1; p++) {
    float v = asrc[csr_src[p] * H + h] + ad;
    v = v > 0.f ? v : NEG_SLOPE * v;
    float ex = expf(v - m);
    alpha[p * H + h] = ex;
    sum += ex;
  }
  float r = 1.f / (sum + EPSV);
  for (int p = s0; p < s1; p++) alpha[p * H + h] *= r;
}

// ---------------------------------------------------------------------------
// Aggregation from bf16 features: acc[n,col] = sum_e alpha[e,h(col)] * h[src_e,col]
// One block per node; thread t owns the 8-wide chunk at col0 = 8*t.
// mode 0: +bias, ELU -> out_f32 AND out_bf    mode 1: +bias +prev, ELU -> out_bf
// mode 2: raw agg -> LDS -> head-mean + b3 -> h3
// ---------------------------------------------------------------------------
__global__ void k_agg(const unsigned short* __restrict__ hfeat, int ldh,
                      const float* __restrict__ alpha,
                      const int* __restrict__ csr_src,
                      const int* __restrict__ offsets,
                      const float* __restrict__ bias,
                      const float* __restrict__ prev,
                      float* __restrict__ out_f32,
                      unsigned short* __restrict__ out_bf,
                      const float* __restrict__ b3,
                      float* __restrict__ h3,
                      int HCv, int C, int H, int mode) {
  int n = blockIdx.x;
  int t = threadIdx.x;
  int nthr = blockDim.x;
  int s0 = offsets[n], s1 = offsets[n + 1];
  int col0 = t * 8;
  bool active = col0 < ldh;

  int hj[8];
  if (active) {
#pragma unroll
    for (int j = 0; j < 8; j++) hj[j] = (col0 + j) / C;  // <= 7 by construction
  }
  float acc[8] = {};

  __shared__ int s_src[64];
  __shared__ float s_alpha[64 * 8];
  __shared__ float s_out[LD3];  // mode-2 reduction buffer

  for (int base = s0; base < s1; base += 64) {
    int chunk = min(64, s1 - base);
    if (t < chunk) s_src[t] = csr_src[base + t];
    for (int i = t; i < chunk * 8; i += nthr) {
      int e = i >> 3, h = i & 7;
      s_alpha[i] = (h < H) ? alpha[(size_t)(base + e) * H + h] : 0.f;
    }
    __syncthreads();
    if (active) {
      for (int e = 0; e < chunk; e++) {
        const unsigned short* hr = hfeat + (size_t)s_src[e] * ldh + col0;
        u16x8 rv = *(const u16x8*)hr;
        const float* al = s_alpha + e * 8;
#pragma unroll
        for (int j = 0; j < 8; j++) acc[j] += al[hj[j]] * bf2f(rv[j]);
      }
    }
    __syncthreads();
  }

  if (mode == 2) {
    if (active) {
#pragma unroll
      for (int j = 0; j < 8; j++) s_out[col0 + j] = acc[j];
    }
    __syncthreads();
    if (t < NCLS)
      h3[(size_t)n * NCLS + t] =
          (s_out[t] + s_out[NCLS + t] + s_out[2 * NCLS + t]) * (1.f / 3.f) + b3[t];
    return;
  }

  if (!active) return;
#pragma unroll
  for (int j = 0; j < 8; j++) {
    int col = col0 + j;
    float v = 0.f;
    if (col < HCv) {
      v = acc[j] + bias[col];
      if (mode == 1) v += prev[(size_t)n * HCv + col];
      v = v > 0.f ? v : (expf(v) - 1.f);  // ELU
      if (out_f32) out_f32[(size_t)n * HCv + col] = v;
    }
    out_bf[(size_t)n * ldh + col] = (col < HCv) ? f2bf(v) : 0;
  }
}

// Pooled column sums
__global__ void k_pool(const float* __restrict__ h3, float* __restrict__ pooled,
                       int N) {
  int col = threadIdx.x;  // blockDim = (64,4)
  if (col >= NCLS) return;
  int row = blockIdx.x * 4 + threadIdx.y;
  int stride = gridDim.x * 4;
  float acc = 0.f;
  for (int r = row; r < N; r += stride) acc += h3[(size_t)r * NCLS + col];
  atomicAdd(&pooled[col], acc);
}

// pooled -> out[0:40], log_softmax(pooled) -> out[40:80]
__global__ __launch_bounds__(64) void k_final(const float* __restrict__ pooled,
                                              float* __restrict__ out) {
  int t = threadIdx.x;
  float v = (t < NCLS) ? pooled[t] : -INFINITY;
  float m = v;
  for (int o = 32; o > 0; o >>= 1) m = fmaxf(m, __shfl_xor(m, o));
  float ex = (t < NCLS) ? expf(v - m) : 0.f;
  float s = ex;
  for (int o = 32; o > 0; o >>= 1) s += __shfl_xor(s, o);
  float lse = m + logf(s);
  if (t < NCLS) {
    out[t] = v;
    out[NCLS + t] = v - lse;
  }
}

// ---------------------------------------------------------------------------
extern "C" void kernel_launch(void* const* d_in, const int* in_sizes, int n_in,
                              void* d_out, int out_size, void* d_ws, size_t ws_size,
                              hipStream_t stream) {
  const float* x   = (const float*)d_in[0];
  const int*   ei  = (const int*)d_in[1];
  const float* W1  = (const float*)d_in[2];
  const float* as1 = (const float*)d_in[3];
  const float* ad1 = (const float*)d_in[4];
  const float* b1  = (const float*)d_in[5];
  const float* W2  = (const float*)d_in[6];
  const float* as2 = (const float*)d_in[7];
  const float* ad2 = (const float*)d_in[8];
  const float* b2  = (const float*)d_in[9];
  const float* W3  = (const float*)d_in[10];
  const float* as3 = (const float*)d_in[11];
  const float* ad3 = (const float*)d_in[12];
  const float* b3  = (const float*)d_in[13];
  float* out = (float*)d_out;

  const int N = NN;
  const int E0 = in_sizes[1] / 2;   // 80000
  const int Etot = E0 + N;          // 90000

  // workspace layout
  float* f = (float*)d_ws;
  float* hbuf1  = f;                               // [N,1500] fp32 (residual)
  float* asrc   = f + (size_t)N * HC1;
  float* adst   = asrc + (size_t)N * H1;
  float* alphab = adst + (size_t)N * H1;           // [Etot,5]
  float* pooled = alphab + (size_t)Etot * H1;      // [64]
  float* h3     = pooled + 64;                     // [N,40]
  int* counts  = (int*)(h3 + (size_t)N * NCLS);
  int* offsets = counts + N;
  int* cursor  = offsets + N + 1;
  int* csr_src = cursor + N;
  uintptr_t pp = (uintptr_t)(csr_src + Etot);
  pp = (pp + 15) & ~(uintptr_t)15;
  unsigned short* hfbf = (unsigned short*)pp;       // [N][KPAD] GEMM output
  unsigned short* abf  = hfbf + (size_t)N * KPAD;   // [N][KPAD] GEMM A input
  unsigned short* btbf = abf + (size_t)N * KPAD;    // [1500][KPAD] W^T

  hipMemsetAsync(counts, 0, (size_t)N * sizeof(int), stream);
  hipMemsetAsync(pooled, 0, 64 * sizeof(float), stream);

  // CSR build
  k_count<<<(Etot + 255) / 256, 256, 0, stream>>>(ei, counts, E0, Etot);
  k_scan<<<1, 256, 0, stream>>>(counts, offsets, cursor, N, Etot);
  k_scatter<<<(Etot + 255) / 256, 256, 0, stream>>>(ei, cursor, csr_src, E0, Etot);

  // ---- Layer 1: GATConv(x; W1) -> hbuf1 (fp32) + abf (bf16), ELU   (K=128)
  {
    k_cvt<<<((long long)N * F_IN + 255) / 256, 256, 0, stream>>>(x, abf, N, F_IN, F_IN);
    dim3 tg((HC1 + 63) / 64, (F_IN + 63) / 64);
    k_cvtT<<<tg, 256, 0, stream>>>(W1, btbf, F_IN, HC1, F_IN);
    dim3 grid((HC1 + BN - 1) / BN, (N + BM - 1) / BM);
    gemm_mfma<<<grid, 256, 0, stream>>>(abf, btbf, hfbf, N, F_IN, HC1, KPAD);
    k_att<<<N, 64, 0, stream>>>(hfbf, KPAD, as1, ad1, asrc, adst, H1, HID);
    k_stats<<<(N * H1 + 255) / 256, 256, 0, stream>>>(asrc, adst, csr_src, offsets,
                                                      alphab, N, H1);
    k_agg<<<N, 192, 0, stream>>>(hfbf, KPAD, alphab, csr_src, offsets, b1, nullptr,
                                 hbuf1, abf, nullptr, nullptr, HC1, HID, H1, 0);
  }

  // ---- Layer 2: GATConv(abf; W2), h = elu(hbuf1 + conv2) -> abf (bf16)  (K=1504)
  {
    dim3 tg((HC1 + 63) / 64, (KPAD + 63) / 64);
    k_cvtT<<<tg, 256, 0, stream>>>(W2, btbf, HC1, HC1, KPAD);
    dim3 grid((HC1 + BN - 1) / BN, (N + BM - 1) / BM);
    gemm_mfma<<<grid, 256, 0, stream>>>(abf, btbf, hfbf, N, KPAD, HC1, KPAD);
    k_att<<<N, 64, 0, stream>>>(hfbf, KPAD, as2, ad2, asrc, adst, H1, HID);
    k_stats<<<(N * H1 + 255) / 256, 256, 0, stream>>>(asrc, adst, csr_src, offsets,
                                                      alphab, N, H1);
    k_agg<<<N, 192, 0, stream>>>(hfbf, KPAD, alphab, csr_src, offsets, b2, hbuf1,
                                 nullptr, abf, nullptr, nullptr, HC1, HID, H1, 1);
  }

  // ---- Layer 3: GATConv(abf; W3), head-mean + b3 -> h3  (K=1504, Nmat=120)
  {
    dim3 tg((HC3 + 63) / 64, (KPAD + 63) / 64);
    k_cvtT<<<tg, 256, 0, stream>>>(W3, btbf, HC1, HC3, KPAD);
    dim3 grid((HC3 + BN - 1) / BN, (N + BM - 1) / BM);
    gemm_mfma<<<grid, 256, 0, stream>>>(abf, btbf, hfbf, N, KPAD, HC3, LD3);
    k_att<<<N, 64, 0, stream>>>(hfbf, LD3, as3, ad3, asrc, adst, H3, NCLS);
    k_stats<<<(N * H3 + 255) / 256, 256, 0, stream>>>(asrc, adst, csr_src, offsets,
                                                      alphab, N, H3);
    k_agg<<<N, 64, 0, stream>>>(hfbf, LD3, alphab, csr_src, offsets, nullptr, nullptr,
                                nullptr, nullptr, b3, h3, HC3, NCLS, H3, 2);
  }

  // ---- Pool + log_softmax
  k_pool<<<64, dim3(64, 4), 0, stream>>>(h3, pooled, N);
  k_final<<<1, 64, 0, stream>>>(pooled, out);
}

// Round 5
// 627.637 us; speedup vs baseline: 1.0383x; 1.0383x over previous
//
#include <hip/hip_runtime.h>
#include <hip/hip_bf16.h>
#include <math.h>

// Problem constants (fixed by the reference)
#define NN       10000      // nodes
#define F_IN     128
#define HID      300
#define H1       5
#define H3       3
#define NCLS     40
#define HC1      (H1*HID)   // 1500
#define HC3      (H3*NCLS)  // 120
#define KPAD     1536       // 1500 padded to multiple of 64 (BK)
#define LD3      128        // layer-3 feature stride (120 padded)
#define NEG_SLOPE 0.2f
#define EPSV     1e-16f

typedef __attribute__((ext_vector_type(8))) short bf16x8;
typedef __attribute__((ext_vector_type(8))) unsigned short u16x8;
typedef __attribute__((ext_vector_type(4))) float f32x4;

__device__ inline unsigned short f2bf(float f) {
  unsigned int u = __builtin_bit_cast(unsigned int, f);
  unsigned int r = (u + 0x7FFFu + ((u >> 16) & 1u)) >> 16;   // RNE
  return (unsigned short)r;
}
__device__ inline float bf2f(unsigned short s) {
  unsigned int u = ((unsigned int)s) << 16;
  return __builtin_bit_cast(float, u);
}

// async 16B/lane global->LDS (lds dest = wave-uniform base + lane*16)
__device__ __forceinline__ void gl2lds16(const unsigned short* g, unsigned short* l) {
  __builtin_amdgcn_global_load_lds(
      (const __attribute__((address_space(1))) unsigned int*)(const void*)g,
      (__attribute__((address_space(3))) unsigned int*)(void*)l, 16, 0, 0);
}

// ---------------------------------------------------------------------------
// CSR build
// ---------------------------------------------------------------------------
__global__ void k_count(const int* __restrict__ ei, int* __restrict__ counts,
                        int E0, int Etot) {
  int e = blockIdx.x * 256 + threadIdx.x;
  if (e >= Etot) return;
  int dst = (e < E0) ? ei[E0 + e] : (e - E0);
  atomicAdd(&counts[dst], 1);
}

__global__ __launch_bounds__(256) void k_scan(const int* __restrict__ counts,
                                              int* __restrict__ offsets,
                                              int* __restrict__ cursor,
                                              int N, int Etot) {
  __shared__ int sh[256];
  const int CH = 40;  // 256*40 = 10240 >= N
  int t = threadIdx.x;
  int base = t * CH;
  int s = 0;
  for (int i = 0; i < CH; i++) {
    int idx = base + i;
    if (idx < N) s += counts[idx];
  }
  sh[t] = s;
  __syncthreads();
  for (int d = 1; d < 256; d <<= 1) {
    int v = (t >= d) ? sh[t - d] : 0;
    __syncthreads();
    sh[t] += v;
    __syncthreads();
  }
  int run = sh[t] - s;  // exclusive prefix
  for (int i = 0; i < CH; i++) {
    int idx = base + i;
    if (idx < N) {
      offsets[idx] = run;
      cursor[idx] = run;
      run += counts[idx];
    }
  }
  if (t == 0) offsets[N] = Etot;
}

__global__ void k_scatter(const int* __restrict__ ei, int* __restrict__ cursor,
                          int* __restrict__ csr_src, int E0, int Etot) {
  int e = blockIdx.x * 256 + threadIdx.x;
  if (e >= Etot) return;
  int src, dst;
  if (e < E0) { src = ei[e]; dst = ei[E0 + e]; }
  else        { src = dst = e - E0; }
  int pos = atomicAdd(&cursor[dst], 1);
  csr_src[pos] = src;
}

// ---------------------------------------------------------------------------
// fp32 -> bf16 casts
// ---------------------------------------------------------------------------
__global__ void k_cvt(const float* __restrict__ in, unsigned short* __restrict__ out,
                      int R, int C, int Cpad) {
  long long idx = (long long)blockIdx.x * 256 + threadIdx.x;
  if (idx >= (long long)R * Cpad) return;
  int r = (int)(idx / Cpad), c = (int)(idx - (long long)r * Cpad);
  out[idx] = (c < C) ? f2bf(in[(size_t)r * C + c]) : 0;
}

// in: [K][Nmat] row-major -> out: [Nmat][Kpad] (transposed, zero-padded)
// 64x64 LDS tile, coalesced on both sides.
__global__ __launch_bounds__(256) void k_cvtT(const float* __restrict__ in,
                                              unsigned short* __restrict__ out,
                                              int K, int Nmat, int Kpad) {
  __shared__ float tile[64][65];
  int kt = blockIdx.y * 64, nt = blockIdx.x * 64;
  int c = threadIdx.x & 63, r = threadIdx.x >> 6;  // 4 rows per pass
  for (int rr = r; rr < 64; rr += 4) {
    int k = kt + rr, n = nt + c;
    tile[rr][c] = (k < K && n < Nmat) ? in[(size_t)k * Nmat + n] : 0.f;
  }
  __syncthreads();
  for (int rr = r; rr < 64; rr += 4) {
    int n = nt + rr, k = kt + c;
    if (n < Nmat && k < Kpad) out[(size_t)n * Kpad + k] = f2bf(tile[c][rr]);
  }
}

// ---------------------------------------------------------------------------
// MFMA GEMM: Cbf[M,ldc] = A[M,Kpad] @ Bt[Nmat,Kpad]^T, bf16 out.
// 128x128 tile, BK=64: 32 MFMA per barrier pair, 24 K-iters at K=1536.
// LDS fragment-ordered: chunk c = rb*2+kh (1KB): lane l's 16B = row rb*16+(l&15),
// k = kh*32 + (l>>4)*8.  global_load_lds width=16; ds_read_b128 conflict-free.
// bm = blockIdx.x (fastest) so consecutive blocks share the B column tile (L2).
// ---------------------------------------------------------------------------
#define BM 128
#define BN 128
#define BK 64

__global__ __launch_bounds__(256) void gemm_mfma(
    const unsigned short* __restrict__ A,   // [M][Kpad]
    const unsigned short* __restrict__ Bt,  // [Nmat][Kpad]
    unsigned short* __restrict__ Cbf,       // [M][ldc]
    int M, int Kpad, int Nmat, int ldc) {
  __shared__ unsigned short As[BM * BK];  // 16 KB
  __shared__ unsigned short Bs[BN * BK];  // 16 KB
  int tid = threadIdx.x;
  int lane = tid & 63, wid = tid >> 6;
  int wm = wid >> 1, wn = wid & 1;
  int bm = blockIdx.x * BM, bn = blockIdx.y * BN;
  int quad = lane >> 4, l16 = lane & 15;
  int kq = quad * 8;

  // wave w stages A row-blocks {2w, 2w+1} and B row-blocks {2w, 2w+1}, kh={0,1}
  int ar0 = min(bm + (2 * wid) * 16 + l16, M - 1);
  int ar1 = min(bm + (2 * wid + 1) * 16 + l16, M - 1);
  int br0 = min(bn + (2 * wid) * 16 + l16, Nmat - 1);
  int br1 = min(bn + (2 * wid + 1) * 16 + l16, Nmat - 1);
  const unsigned short* gA0 = A + (size_t)ar0 * Kpad + kq;
  const unsigned short* gA1 = A + (size_t)ar1 * Kpad + kq;
  const unsigned short* gB0 = Bt + (size_t)br0 * Kpad + kq;
  const unsigned short* gB1 = Bt + (size_t)br1 * Kpad + kq;
  unsigned short* lA = As + 4 * wid * 512;  // chunks 4w .. 4w+3
  unsigned short* lB = Bs + 4 * wid * 512;

  f32x4 acc[4][4] = {};

  for (int kt = 0; kt < Kpad; kt += BK) {
    gl2lds16(gA0 + kt,      lA);
    gl2lds16(gA0 + kt + 32, lA + 512);
    gl2lds16(gA1 + kt,      lA + 1024);
    gl2lds16(gA1 + kt + 32, lA + 1536);
    gl2lds16(gB0 + kt,      lB);
    gl2lds16(gB0 + kt + 32, lB + 512);
    gl2lds16(gB1 + kt,      lB + 1024);
    gl2lds16(gB1 + kt + 32, lB + 1536);
    __syncthreads();
#pragma unroll
    for (int kh = 0; kh < 2; kh++) {
      bf16x8 af[4], bfr[4];
#pragma unroll
      for (int i = 0; i < 4; i++) {
        af[i]  = *(const bf16x8*)(As + ((wm * 4 + i) * 2 + kh) * 512 + lane * 8);
        bfr[i] = *(const bf16x8*)(Bs + ((wn * 4 + i) * 2 + kh) * 512 + lane * 8);
      }
#pragma unroll
      for (int i = 0; i < 4; i++)
#pragma unroll
        for (int j = 0; j < 4; j++)
          acc[i][j] = __builtin_amdgcn_mfma_f32_16x16x32_bf16(af[i], bfr[j], acc[i][j], 0, 0, 0);
    }
    __syncthreads();
  }

#pragma unroll
  for (int i = 0; i < 4; i++) {
    int rowb = bm + wm * 64 + i * 16 + quad * 4;
#pragma unroll
    for (int j = 0; j < 4; j++) {
      int col = bn + wn * 64 + j * 16 + l16;
      if (col < ldc) {
        bool live = col < Nmat;
#pragma unroll
        for (int r = 0; r < 4; r++) {
          int row = rowb + r;
          if (row < M) Cbf[(size_t)row * ldc + col] = live ? f2bf(acc[i][j][r]) : 0;
        }
      }
    }
  }
}

// ---------------------------------------------------------------------------
// Attention coefficients from bf16 features
// ---------------------------------------------------------------------------
__global__ __launch_bounds__(64) void k_att(const unsigned short* __restrict__ hfeat,
                                            int ldh,
                                            const float* __restrict__ att_s,
                                            const float* __restrict__ att_d,
                                            float* __restrict__ asrc,
                                            float* __restrict__ adst,
                                            int H, int C) {
  int n = blockIdx.x;
  int t = threadIdx.x;
  const unsigned short* hr = hfeat + (size_t)n * ldh;
  for (int h = 0; h < H; h++) {
    float ps = 0.f, pd = 0.f;
    for (int c = t; c < C; c += 64) {
      float v = bf2f(hr[h * C + c]);
      ps += v * att_s[h * C + c];
      pd += v * att_d[h * C + c];
    }
    for (int o = 32; o > 0; o >>= 1) {
      ps += __shfl_down(ps, o);
      pd += __shfl_down(pd, o);
    }
    if (t == 0) {
      asrc[n * H + h] = ps;
      adst[n * H + h] = pd;
    }
  }
}

// ---------------------------------------------------------------------------
// Per-(node,head) softmax over incoming edges; writes normalized alpha.
// ---------------------------------------------------------------------------
__global__ void k_stats(const float* __restrict__ asrc,
                        const float* __restrict__ adst,
                        const int* __restrict__ csr_src,
                        const int* __restrict__ offsets,
                        float* __restrict__ alpha, int N, int H) {
  int t = blockIdx.x * 256 + threadIdx.x;
  if (t >= N * H) return;
  int n = t / H, h = t - n * H;
  int s0 = offsets[n], s1 = offsets[n + 1];
  float ad = adst[t];
  float m = -1e30f;
  for (int p = s0; p < s1; p++) {
    float v = asrc[csr_src[p] * H + h] + ad;
    v = v > 0.f ? v : NEG_SLOPE * v;
    m = fmaxf(m, v);
  }
  float sum = 0.f;
  for (int p = s0; p < s1; p++) {
    float v = asrc[csr_src[p] * H + h] + ad;
    v = v > 0.f ? v : NEG_SLOPE * v;
    float ex = expf(v - m);
    alpha[p * H + h] = ex;
    sum += ex;
  }
  float r = 1.f / (sum + EPSV);
  for (int p = s0; p < s1; p++) alpha[p * H + h] *= r;
}

// ---------------------------------------------------------------------------
// Aggregation from bf16 features: acc[n,col] = sum_e alpha[e,h(col)] * h[src_e,col]
// One block per node; thread t owns the 8-wide chunk at col0 = 8*t.
// mode 0: +bias, ELU -> out_f32 AND out_bf    mode 1: +bias +prev, ELU -> out_bf
// mode 2: raw agg -> LDS -> head-mean + b3 -> h3
// 2-stage software pipeline on the gathered row loads.
// ---------------------------------------------------------------------------
__global__ void k_agg(const unsigned short* __restrict__ hfeat, int ldh,
                      const float* __restrict__ alpha,
                      const int* __restrict__ csr_src,
                      const int* __restrict__ offsets,
                      const float* __restrict__ bias,
                      const float* __restrict__ prev,
                      float* __restrict__ out_f32,
                      unsigned short* __restrict__ out_bf,
                      const float* __restrict__ b3,
                      float* __restrict__ h3,
                      int HCv, int C, int H, int mode) {
  int n = blockIdx.x;
  int t = threadIdx.x;
  int nthr = blockDim.x;
  int s0 = offsets[n], s1 = offsets[n + 1];
  int col0 = t * 8;
  bool active = col0 < ldh;

  int hj[8];
  if (active) {
#pragma unroll
    for (int j = 0; j < 8; j++) hj[j] = (col0 + j) / C;  // <= 7 by construction
  }
  float acc[8] = {};

  __shared__ int s_src[64];
  __shared__ float s_alpha[64 * 8];
  __shared__ float s_out[LD3];  // mode-2 reduction buffer

  for (int base = s0; base < s1; base += 64) {
    int chunk = min(64, s1 - base);
    if (t < chunk) s_src[t] = csr_src[base + t];
    for (int i = t; i < chunk * 8; i += nthr) {
      int e = i >> 3, h = i & 7;
      s_alpha[i] = (h < H) ? alpha[(size_t)(base + e) * H + h] : 0.f;
    }
    __syncthreads();
    if (active) {
      u16x8 rv = *(const u16x8*)(hfeat + (size_t)s_src[0] * ldh + col0);
      for (int e = 0; e < chunk; e++) {
        u16x8 cur = rv;
        if (e + 1 < chunk)
          rv = *(const u16x8*)(hfeat + (size_t)s_src[e + 1] * ldh + col0);
        const float* al = s_alpha + e * 8;
#pragma unroll
        for (int j = 0; j < 8; j++) acc[j] += al[hj[j]] * bf2f(cur[j]);
      }
    }
    __syncthreads();
  }

  if (mode == 2) {
    if (active) {
#pragma unroll
      for (int j = 0; j < 8; j++) s_out[col0 + j] = acc[j];
    }
    __syncthreads();
    if (t < NCLS)
      h3[(size_t)n * NCLS + t] =
          (s_out[t] + s_out[NCLS + t] + s_out[2 * NCLS + t]) * (1.f / 3.f) + b3[t];
    return;
  }

  if (!active) return;
#pragma unroll
  for (int j = 0; j < 8; j++) {
    int col = col0 + j;
    float v = 0.f;
    if (col < HCv) {
      v = acc[j] + bias[col];
      if (mode == 1) v += prev[(size_t)n * HCv + col];
      v = v > 0.f ? v : (expf(v) - 1.f);  // ELU
      if (out_f32) out_f32[(size_t)n * HCv + col] = v;
    }
    out_bf[(size_t)n * ldh + col] = (col < HCv) ? f2bf(v) : 0;
  }
}

// Pooled column sums
__global__ void k_pool(const float* __restrict__ h3, float* __restrict__ pooled,
                       int N) {
  int col = threadIdx.x;  // blockDim = (64,4)
  if (col >= NCLS) return;
  int row = blockIdx.x * 4 + threadIdx.y;
  int stride = gridDim.x * 4;
  float acc = 0.f;
  for (int r = row; r < N; r += stride) acc += h3[(size_t)r * NCLS + col];
  atomicAdd(&pooled[col], acc);
}

// pooled -> out[0:40], log_softmax(pooled) -> out[40:80]
__global__ __launch_bounds__(64) void k_final(const float* __restrict__ pooled,
                                              float* __restrict__ out) {
  int t = threadIdx.x;
  float v = (t < NCLS) ? pooled[t] : -INFINITY;
  float m = v;
  for (int o = 32; o > 0; o >>= 1) m = fmaxf(m, __shfl_xor(m, o));
  float ex = (t < NCLS) ? expf(v - m) : 0.f;
  float s = ex;
  for (int o = 32; o > 0; o >>= 1) s += __shfl_xor(s, o);
  float lse = m + logf(s);
  if (t < NCLS) {
    out[t] = v;
    out[NCLS + t] = v - lse;
  }
}

// ---------------------------------------------------------------------------
extern "C" void kernel_launch(void* const* d_in, const int* in_sizes, int n_in,
                              void* d_out, int out_size, void* d_ws, size_t ws_size,
                              hipStream_t stream) {
  const float* x   = (const float*)d_in[0];
  const int*   ei  = (const int*)d_in[1];
  const float* W1  = (const float*)d_in[2];
  const float* as1 = (const float*)d_in[3];
  const float* ad1 = (const float*)d_in[4];
  const float* b1  = (const float*)d_in[5];
  const float* W2  = (const float*)d_in[6];
  const float* as2 = (const float*)d_in[7];
  const float* ad2 = (const float*)d_in[8];
  const float* b2  = (const float*)d_in[9];
  const float* W3  = (const float*)d_in[10];
  const float* as3 = (const float*)d_in[11];
  const float* ad3 = (const float*)d_in[12];
  const float* b3  = (const float*)d_in[13];
  float* out = (float*)d_out;

  const int N = NN;
  const int E0 = in_sizes[1] / 2;   // 80000
  const int Etot = E0 + N;          // 90000

  // workspace layout
  float* f = (float*)d_ws;
  float* hbuf1  = f;                               // [N,1500] fp32 (residual)
  float* asrc   = f + (size_t)N * HC1;
  float* adst   = asrc + (size_t)N * H1;
  float* alphab = adst + (size_t)N * H1;           // [Etot,5]
  float* pooled = alphab + (size_t)Etot * H1;      // [64]
  float* h3     = pooled + 64;                     // [N,40]
  int* counts  = (int*)(h3 + (size_t)N * NCLS);
  int* offsets = counts + N;
  int* cursor  = offsets + N + 1;
  int* csr_src = cursor + N;
  uintptr_t pp = (uintptr_t)(csr_src + Etot);
  pp = (pp + 15) & ~(uintptr_t)15;
  unsigned short* hfbf = (unsigned short*)pp;       // [N][KPAD] GEMM output
  unsigned short* abf  = hfbf + (size_t)N * KPAD;   // [N][KPAD] GEMM A input
  unsigned short* btbf = abf + (size_t)N * KPAD;    // [1500][KPAD] W^T

  hipMemsetAsync(counts, 0, (size_t)N * sizeof(int), stream);
  hipMemsetAsync(pooled, 0, 64 * sizeof(float), stream);

  // CSR build
  k_count<<<(Etot + 255) / 256, 256, 0, stream>>>(ei, counts, E0, Etot);
  k_scan<<<1, 256, 0, stream>>>(counts, offsets, cursor, N, Etot);
  k_scatter<<<(Etot + 255) / 256, 256, 0, stream>>>(ei, cursor, csr_src, E0, Etot);

  // ---- Layer 1: GATConv(x; W1) -> hbuf1 (fp32) + abf (bf16), ELU   (K=128)
  {
    k_cvt<<<((long long)N * F_IN + 255) / 256, 256, 0, stream>>>(x, abf, N, F_IN, F_IN);
    dim3 tg((HC1 + 63) / 64, (F_IN + 63) / 64);
    k_cvtT<<<tg, 256, 0, stream>>>(W1, btbf, F_IN, HC1, F_IN);
    dim3 grid((N + BM - 1) / BM, (HC1 + BN - 1) / BN);
    gemm_mfma<<<grid, 256, 0, stream>>>(abf, btbf, hfbf, N, F_IN, HC1, KPAD);
    k_att<<<N, 64, 0, stream>>>(hfbf, KPAD, as1, ad1, asrc, adst, H1, HID);
    k_stats<<<(N * H1 + 255) / 256, 256, 0, stream>>>(asrc, adst, csr_src, offsets,
                                                      alphab, N, H1);
    k_agg<<<N, 192, 0, stream>>>(hfbf, KPAD, alphab, csr_src, offsets, b1, nullptr,
                                 hbuf1, abf, nullptr, nullptr, HC1, HID, H1, 0);
  }

  // ---- Layer 2: GATConv(abf; W2), h = elu(hbuf1 + conv2) -> abf (bf16)  (K=1536)
  {
    dim3 tg((HC1 + 63) / 64, (KPAD + 63) / 64);
    k_cvtT<<<tg, 256, 0, stream>>>(W2, btbf, HC1, HC1, KPAD);
    dim3 grid((N + BM - 1) / BM, (HC1 + BN - 1) / BN);
    gemm_mfma<<<grid, 256, 0, stream>>>(abf, btbf, hfbf, N, KPAD, HC1, KPAD);
    k_att<<<N, 64, 0, stream>>>(hfbf, KPAD, as2, ad2, asrc, adst, H1, HID);
    k_stats<<<(N * H1 + 255) / 256, 256, 0, stream>>>(asrc, adst, csr_src, offsets,
                                                      alphab, N, H1);
    k_agg<<<N, 192, 0, stream>>>(hfbf, KPAD, alphab, csr_src, offsets, b2, hbuf1,
                                 nullptr, abf, nullptr, nullptr, HC1, HID, H1, 1);
  }

  // ---- Layer 3: GATConv(abf; W3), head-mean + b3 -> h3  (K=1536, Nmat=120)
  {
    dim3 tg((HC3 + 63) / 64, (KPAD + 63) / 64);
    k_cvtT<<<tg, 256, 0, stream>>>(W3, btbf, HC1, HC3, KPAD);
    dim3 grid((N + BM - 1) / BM, (HC3 + BN - 1) / BN);
    gemm_mfma<<<grid, 256, 0, stream>>>(abf, btbf, hfbf, N, KPAD, HC3, LD3);
    k_att<<<N, 64, 0, stream>>>(hfbf, LD3, as3, ad3, asrc, adst, H3, NCLS);
    k_stats<<<(N * H3 + 255) / 256, 256, 0, stream>>>(asrc, adst, csr_src, offsets,
                                                      alphab, N, H3);
    k_agg<<<N, 64, 0, stream>>>(hfbf, LD3, alphab, csr_src, offsets, nullptr, nullptr,
                                nullptr, nullptr, b3, h3, HC3, NCLS, H3, 2);
  }

  // ---- Pool + log_softmax
  k_pool<<<64, dim3(64, 4), 0, stream>>>(h3, pooled, N);
  k_final<<<1, 64, 0, stream>>>(pooled, out);
}